// Round 3
// baseline (274.196 us; speedup 1.0000x reference)
//
#include <hip/hip_runtime.h>
#include <math.h>

#define B_TOT 2048
#define IN_TOT 512
#define OUT_TOT 512
#define ROWS 32          // rows per block
#define COLS 64          // cols per block
#define RNDS 8           // 8 rounds x 16 k/wave x 4 waves = 512 k

__global__ __launch_bounds__(256, 2) void morph_kernel(
    const float* __restrict__ x,
    const float* __restrict__ wdil,
    const float* __restrict__ wero,
    float* __restrict__ out)
{
    // [buf][arr][col*64 + quad*4 + e] : 2*2*4096 floats = 64 KB
    // reused as partial buffer in the epilogue (dil [0,8192), ero [8192,16384))
    __shared__ float wbuf[2][2][4096];

    const int tid  = (int)threadIdx.x;
    const int lane = tid & 63;
    const int wv   = tid >> 6;     // wave = k-partition: k in [wv*128, wv*128+128)
    const int tx   = lane & 15;    // col group: cols {tx, tx+16, tx+32, tx+48}
    const int ty   = lane >> 4;    // row group: rows {ty, ty+4, ..., ty+28}

    const int row0 = (int)blockIdx.y * ROWS;
    const int col0 = (int)blockIdx.x * COLS;

    // ---- weight staging map (quad-XOR swizzle, source-side) ----
    // slot s: col c = s>>4, phys quad Q = s&15 holds logical quad L = Q^(c&15)
    // logical quad L -> k = (L>>2)*128 + r*16 + (L&3)*4
    int soff[4], lws[4];
#pragma unroll
    for (int i = 0; i < 4; ++i) {
        int s = i * 256 + tid;
        int c = s >> 4, Q = s & 15;
        int L = Q ^ (c & 15);
        soff[i] = (col0 + c) * IN_TOT + (L >> 2) * 128 + (L & 3) * 4;
        lws[i]  = s * 4;           // linear LDS float offset (canonical b128)
    }

    const float* xbase = x + (size_t)(row0 + ty) * IN_TOT + wv * 128;

    float dil[8][4], ero[8][4];
#pragma unroll
    for (int mi = 0; mi < 8; ++mi)
#pragma unroll
        for (int n = 0; n < 4; ++n) { dil[mi][n] = -INFINITY; ero[mi][n] = INFINITY; }

    // ---- prologue: stage round 0 into buf 0 ----
#pragma unroll
    for (int i = 0; i < 4; ++i) {
        *(float4*)&wbuf[0][0][lws[i]] = *(const float4*)(wdil + soff[i]);
        *(float4*)&wbuf[0][1][lws[i]] = *(const float4*)(wero + soff[i]);
    }
    __syncthreads();

#pragma unroll 1
    for (int r = 0; r < RNDS; ++r) {
        const int buf = r & 1;
        float4 sa[4], sb[4];
        if (r + 1 < RNDS) {        // T14: issue next round's loads early
#pragma unroll
            for (int i = 0; i < 4; ++i) {
                sa[i] = *(const float4*)(wdil + soff[i] + (r + 1) * 16);
                sb[i] = *(const float4*)(wero + soff[i] + (r + 1) * 16);
            }
        }

        const float* __restrict__ wdp = wbuf[buf][0];
        const float* __restrict__ wep = wbuf[buf][1];

#pragma unroll
        for (int kks = 0; kks < 4; ++kks) {
            const int qf = ((((wv << 2) + kks) ^ tx) << 2);
            float4 wd4[4], we4[4];
#pragma unroll
            for (int n = 0; n < 4; ++n) {
                const int off = (tx + 16 * n) * 64 + qf;
                wd4[n] = *(const float4*)(wdp + off);   // 2-way max: free
                we4[n] = *(const float4*)(wep + off);
            }
#pragma unroll
            for (int mi = 0; mi < 8; ++mi) {
                float4 xv = *(const float4*)(xbase + mi * (4 * IN_TOT) + r * 16 + kks * 4);
#pragma unroll
                for (int n = 0; n < 4; ++n) {
                    dil[mi][n] = fmaxf(fmaxf(xv.x + wd4[n].x, xv.y + wd4[n].y),
                                 fmaxf(fmaxf(xv.z + wd4[n].z, xv.w + wd4[n].w), dil[mi][n]));
                    ero[mi][n] = fminf(fminf(xv.x - we4[n].x, xv.y - we4[n].y),
                                 fminf(fminf(xv.z - we4[n].z, xv.w - we4[n].w), ero[mi][n]));
                }
            }
        }

        if (r + 1 < RNDS) {        // write-late into the other buffer
            const int nb = buf ^ 1;
#pragma unroll
            for (int i = 0; i < 4; ++i) {
                *(float4*)&wbuf[nb][0][lws[i]] = sa[i];
                *(float4*)&wbuf[nb][1][lws[i]] = sb[i];
            }
        }
        __syncthreads();
    }

    // ---- epilogue: cross-wave k-combine via reused LDS ----
    float* pb = &wbuf[0][0][0];    // 16384 floats
#pragma unroll
    for (int mi = 0; mi < 8; ++mi) {
        const int row = ty + 4 * mi;
        const int rb  = wv * 2048 + row * 64;
        const int sw  = (row & 3) << 4;
#pragma unroll
        for (int n = 0; n < 4; ++n) {
            const int cs = (tx + 16 * n) ^ sw;
            pb[rb + cs]        = dil[mi][n];
            pb[8192 + rb + cs] = ero[mi][n];
        }
    }
    __syncthreads();

    const int rr = tid >> 3;            // 0..31
    const int cc = (tid & 7) * 8;       // 8 consecutive cols
    const int bo = rr * 64 + (cc ^ ((rr & 3) << 4));

    float4 d0 = *(float4*)&pb[bo],        d1 = *(float4*)&pb[bo + 4];
    float4 e0 = *(float4*)&pb[8192 + bo], e1 = *(float4*)&pb[8192 + bo + 4];
#pragma unroll
    for (int w2 = 1; w2 < 4; ++w2) {
        float4 t0 = *(float4*)&pb[w2 * 2048 + bo];
        float4 t1 = *(float4*)&pb[w2 * 2048 + bo + 4];
        d0.x = fmaxf(d0.x, t0.x); d0.y = fmaxf(d0.y, t0.y);
        d0.z = fmaxf(d0.z, t0.z); d0.w = fmaxf(d0.w, t0.w);
        d1.x = fmaxf(d1.x, t1.x); d1.y = fmaxf(d1.y, t1.y);
        d1.z = fmaxf(d1.z, t1.z); d1.w = fmaxf(d1.w, t1.w);
        float4 u0 = *(float4*)&pb[8192 + w2 * 2048 + bo];
        float4 u1 = *(float4*)&pb[8192 + w2 * 2048 + bo + 4];
        e0.x = fminf(e0.x, u0.x); e0.y = fminf(e0.y, u0.y);
        e0.z = fminf(e0.z, u0.z); e0.w = fminf(e0.w, u0.w);
        e1.x = fminf(e1.x, u1.x); e1.y = fminf(e1.y, u1.y);
        e1.z = fminf(e1.z, u1.z); e1.w = fminf(e1.w, u1.w);
    }
    float4 o0, o1;
    o0.x = d0.x + e0.x; o0.y = d0.y + e0.y; o0.z = d0.z + e0.z; o0.w = d0.w + e0.w;
    o1.x = d1.x + e1.x; o1.y = d1.y + e1.y; o1.z = d1.z + e1.z; o1.w = d1.w + e1.w;

    float* op = out + (size_t)(row0 + rr) * OUT_TOT + col0 + cc;
    *(float4*)op       = o0;
    *(float4*)(op + 4) = o1;
}

extern "C" void kernel_launch(void* const* d_in, const int* in_sizes, int n_in,
                              void* d_out, int out_size, void* d_ws, size_t ws_size,
                              hipStream_t stream)
{
    const float* x  = (const float*)d_in[0];
    const float* wd = (const float*)d_in[1];
    const float* we = (const float*)d_in[2];
    float* out = (float*)d_out;

    dim3 grid(OUT_TOT / COLS, B_TOT / ROWS);   // (8, 64) = 512 blocks = 2/CU
    dim3 block(256);
    hipLaunchKernelGGL(morph_kernel, grid, block, 0, stream, x, wd, we, out);
}

// Round 4
// 85.662 us; speedup vs baseline: 3.2009x; 3.2009x over previous
//
#include <hip/hip_runtime.h>
#include <math.h>

#define B_TOT 2048
#define IN_TOT 512
#define OUT_TOT 512
#define CPB 16            // cols per block
#define RPB 128           // rows per block (16 ty-slots x m=8)
#define M 8               // rows per thread

__global__ __launch_bounds__(256, 2) void morph_kernel(
    const float* __restrict__ x,
    const float* __restrict__ wdil,
    const float* __restrict__ wero,
    float* __restrict__ out)
{
    // [arr][col*512 + phys_quad*4 + e] : 2 * 16 cols * 512 k * 4B = 64 KB
    // staged ONCE; no barriers in the main loop.
    __shared__ float w_s[2][CPB * IN_TOT];

    const int tid = (int)threadIdx.x;
    const int tx  = tid & 15;     // col within block
    const int ty  = tid >> 4;     // row slot: rows ty + 16*mi

    const int col0 = (int)blockIdx.x * CPB;
    const int row0 = (int)blockIdx.y * RPB;

    // ---- stage weights, source-side quad-XOR swizzle (m173 pattern) ----
    // slot s: col c = s>>7, phys quad qp = s&127 holds logical quad
    // ql = (qp&112) | ((qp&15) ^ c).  Read back: phys = (q&112)|((q&15)^tx).
#pragma unroll
    for (int i = 0; i < 8; ++i) {
        const int s  = i * 256 + tid;           // quad slot in [0,2048)
        const int c  = s >> 7;
        const int qp = s & 127;
        const int ql = (qp & 112) | ((qp & 15) ^ c);
        const int g  = (col0 + c) * IN_TOT + ql * 4;
        *(float4*)&w_s[0][s * 4] = *(const float4*)(wdil + g);
        *(float4*)&w_s[1][s * 4] = *(const float4*)(wero + g);
    }
    __syncthreads();   // the only barrier

    float dil[M], ero[M];
#pragma unroll
    for (int mi = 0; mi < M; ++mi) { dil[mi] = -INFINITY; ero[mi] = INFINITY; }

    const float* xr[M];
#pragma unroll
    for (int mi = 0; mi < M; ++mi)
        xr[mi] = x + (size_t)(row0 + ty + 16 * mi) * IN_TOT;

    const float* __restrict__ wdp = &w_s[0][tx * IN_TOT];
    const float* __restrict__ wep = &w_s[1][tx * IN_TOT];

#pragma unroll 1
    for (int hi = 0; hi < 8; ++hi) {
#pragma unroll
        for (int lo = 0; lo < 16; ++lo) {
            const int ph = hi * 16 + (lo ^ tx);     // swizzled quad -> 2-way, free
            float4 wd4 = *(const float4*)(wdp + ph * 4);
            float4 we4 = *(const float4*)(wep + ph * 4);
            const int k4 = (hi * 16 + lo) * 4;
#pragma unroll
            for (int mi = 0; mi < M; ++mi) {
                float4 xv = *(const float4*)(xr[mi] + k4);  // 16-lane broadcast, L1-hot
                dil[mi] = fmaxf(fmaxf(xv.x + wd4.x, xv.y + wd4.y), dil[mi]);
                dil[mi] = fmaxf(fmaxf(xv.z + wd4.z, xv.w + wd4.w), dil[mi]);
                ero[mi] = fminf(fminf(xv.x - we4.x, xv.y - we4.y), ero[mi]);
                ero[mi] = fminf(fminf(xv.z - we4.z, xv.w - we4.w), ero[mi]);
            }
        }
    }

    float* op = out + (size_t)(row0 + ty) * OUT_TOT + col0 + tx;
#pragma unroll
    for (int mi = 0; mi < M; ++mi)
        op[(size_t)16 * mi * OUT_TOT] = dil[mi] + ero[mi];
}

extern "C" void kernel_launch(void* const* d_in, const int* in_sizes, int n_in,
                              void* d_out, int out_size, void* d_ws, size_t ws_size,
                              hipStream_t stream)
{
    const float* x  = (const float*)d_in[0];
    const float* wd = (const float*)d_in[1];
    const float* we = (const float*)d_in[2];
    float* out = (float*)d_out;

    dim3 grid(OUT_TOT / CPB, B_TOT / RPB);   // (32, 16) = 512 blocks = 2/CU
    dim3 block(256);
    hipLaunchKernelGGL(morph_kernel, grid, block, 0, stream, x, wd, we, out);
}